// Round 19
// baseline (382.188 us; speedup 1.0000x reference)
//
#include <hip/hip_runtime.h>
#include <hip/hip_bf16.h>

#define B_    16
#define C_    96
#define H_    224
#define W_    224
#define COUT_ 96
#define GH_   14
#define GW_   14
#define P_    196          // GH_*GW_
#define HW_   (H_*W_)      // 50176
#define NCH_  12           // 8-channel chunks

#define AS1 __attribute__((address_space(1)))
#define AS3 __attribute__((address_space(3)))

typedef __attribute__((ext_vector_type(8))) unsigned short ushort8;
typedef __attribute__((ext_vector_type(8))) short        short8;   // MFMA bf16x8 operand
typedef __attribute__((ext_vector_type(4))) float        f32x4;

__device__ __forceinline__ unsigned short f2bf(float f) {
    union { __hip_bfloat16 h; unsigned short u; } cv;
    cv.h = __float2bfloat16(f);
    return cv.u;
}

// ---------------------------------------------------------------------------
// Kernel 0: of (COUT,C,3,3) f32 -> ofb3 in MFMA-FRAGMENT ORDER:
//   ofb3[tap][cs][ni][lane][8ch],  lane = mrow + 16*kgrp,
//   cout = ni*16 + (lane&15), c = cs*32 + (lane>>4)*8 + j.
// Wave bf load = base + lane*16B: coalesced 1 KB, same across waves.
// ---------------------------------------------------------------------------
__global__ __launch_bounds__(256) void prep_ofb(const float* __restrict__ of,
                                                unsigned short* __restrict__ ofb3,
                                                unsigned short* __restrict__ zp) {
    if (blockIdx.x == 0 && threadIdx.x < 128) zp[threadIdx.x] = 0;
    int e = blockIdx.x * 256 + threadIdx.x;        // 9*3*6*64*8 = 82944
    if (e < 82944) {
        int j    = e & 7;
        int l    = (e >> 3) & 63;
        int ni   = (e >> 9) % 6;
        int cs   = (e / 3072) % 3;
        int tap  = e / 9216;
        int cout = ni * 16 + (l & 15);
        int c    = cs * 32 + (l >> 4) * 8 + j;
        ofb3[e] = f2bf(of[((size_t)cout * 96 + c) * 9 + tap]);
    }
}

// ---------------------------------------------------------------------------
// Kernel 1: per-patch depthwise 3x3 (patch-local zero padding).
// x: (B,C,H,W) f32 -> sa: (B, 12, H, W, 8) bf16  (8-ch chunk planes).
// (R5-proven: ~107 us, near traffic floor. Unchanged.)
// ---------------------------------------------------------------------------
__global__ __launch_bounds__(256) void sa_kernel(const float* __restrict__ x,
                                                 const float* __restrict__ pf,
                                                 unsigned short* __restrict__ sa) {
    int bid   = blockIdx.x;
    int patch = bid % P_;
    int b     = bid / P_;
    int gh = patch / GW_, gw = patch % GW_;
    int t  = threadIdx.x;
    int py = t >> 4, px = t & 15;
    int y  = gh * 16 + py, xx = gw * 16 + px;

    __shared__ float xs[2][8][256];    // 16 KB double-buffered x slice

    const float* xp0 = x + (size_t)b * C_ * HW_ + (size_t)y * W_ + xx;

    float lf[8];
    #pragma unroll
    for (int ch = 0; ch < 8; ++ch) lf[ch] = xp0[(size_t)ch * HW_];

    for (int cc = 0; cc < NCH_; ++cc) {
        int buf = cc & 1;
        #pragma unroll
        for (int ch = 0; ch < 8; ++ch) xs[buf][ch][t] = lf[ch];
        __syncthreads();
        if (cc < NCH_ - 1) {
            #pragma unroll
            for (int ch = 0; ch < 8; ++ch)
                lf[ch] = xp0[(size_t)((cc + 1) * 8 + ch) * HW_];
        }

        ushort8 v;
        #pragma unroll
        for (int ch = 0; ch < 8; ++ch) {
            const float* wgt = pf + ((size_t)(cc * 8 + ch) * P_ + patch) * 9;  // uniform -> s_load
            float a = 0.f;
            #pragma unroll
            for (int dy = -1; dy <= 1; ++dy) {
                int yy = py + dy;
                if ((unsigned)yy < 16u) {
                    #pragma unroll
                    for (int dx = -1; dx <= 1; ++dx) {
                        int xq = px + dx;
                        if ((unsigned)xq < 16u)
                            a = fmaf(xs[buf][ch][yy * 16 + xq],
                                     wgt[(dy + 1) * 3 + (dx + 1)], a);
                    }
                }
            }
            v[ch] = f2bf(a);
        }
        *(ushort8*)&sa[(((size_t)(b * NCH_ + cc) * H_ + y) * W_ + xx) * 8] = v;
    }
}

// ---------------------------------------------------------------------------
// Kernel 2: implicit-GEMM MFMA conv + exact GELU, HALF-PATCH blocks.
// R19 = R17's proven bf fence-pipeline at 1.5x the TLP:
//   - block = 8x16 px x 96 couts, 256 thr / 4 waves (2M x 2N);
//     wave = 64 px x 48 couts, acc[4][3] = 48 AGPR;
//   - A: 10x18 halo x 12 planes, PLANE-MAJOR [ccl][180px] (R12-proven:
//     af reads 16-lane-contiguous -> measured-halved bank conflicts),
//     staged ONCE via global_load_lds (36,864 B), one barrier;
//   - bf depth-1 double-buffer bfA/bfB + sched_barrier(0) fence (R17:
//     272->250; depth-2 and setprio were measured nulls in R18, reverted);
//   - launch_bounds(256,3): budget 170 -> ~122 arch regs after 48 AGPR,
//     fits the ~90-reg pipeline; LDS 36.9K x 3 -> 3 blocks/CU = 3 waves/SIMD
//     (m97's occupancy, vs R17's 2) -- the missing latency cover.
// ---------------------------------------------------------------------------
__global__ __launch_bounds__(256, 3) void conv2_mfma(const unsigned short* __restrict__ sa,
                                                     const unsigned short* __restrict__ ofb3,
                                                     const unsigned short* __restrict__ zp,
                                                     float* __restrict__ out) {
    // XCD-aware swizzle (6272 % 8 == 0 -> bijective); same-patch halves adjacent
    int bid0 = blockIdx.x;
    int bid  = (bid0 % 8) * (6272 / 8) + bid0 / 8;
    int half = bid & 1;
    int pid  = bid >> 1;
    int patch = pid % P_;
    int b     = pid / P_;
    int gh = patch / GW_, gw = patch % GW_;
    int y0 = gh * 16 + half * 8, x0 = gw * 16;   // 8x16 output region

    int t = threadIdx.x;
    int w = t >> 6, l = t & 63;
    int wm = w & 1, wn = w >> 1;            // 2 M-waves x 2 N-waves
    int mrow = l & 15, kgrp = l >> 4;

    __shared__ ushort8 at8[2304];           // 12 planes x 180 px + 144 trash = 36,864 B

    // ---- single staging burst: 10x18 halo, plane-major [ccl][180] ----
    #pragma unroll
    for (int i = 0; i < 9; ++i) {
        int v = t + i * 256;                // 0..2303; [0,2160) real
        const unsigned short* src = zp;
        if (v < 2160) {
            int ccl = v / 180, hpx = v - ccl * 180;
            int gy = y0 - 1 + hpx / 18, gx = x0 - 1 + hpx % 18;
            if ((unsigned)gy < (unsigned)H_ && (unsigned)gx < (unsigned)W_)
                src = &sa[(((size_t)(b * NCH_ + ccl) * H_ + gy) * W_ + gx) * 8];
        }
        __builtin_amdgcn_global_load_lds((const AS1 unsigned int*)src,
                                         (AS3 unsigned int*)&at8[v], 16, 0, 0);
    }

    f32x4 acc[4][3];
    #pragma unroll
    for (int mi = 0; mi < 4; ++mi)
        #pragma unroll
        for (int ni = 0; ni < 3; ++ni)
            acc[mi][ni] = (f32x4)0.f;

    __syncthreads();                        // drain DMA; tile visible; queue EMPTY

    const unsigned short* at = (const unsigned short*)at8;  // [plane][180 px][8ch]

    // bf fetch for step T (tap = T/3, cs = T%3); wave wn's 3 couts-of-16
    short8 bfA[3], bfB[3];
    auto LOADBF = [&](short8* dst, int T) {
        const unsigned short* p = ofb3 + (size_t)(T / 3) * 9216 + (T % 3) * 3072
                                  + (wn * 3) * 512 + l * 8;
        #pragma unroll
        for (int nj = 0; nj < 3; ++nj)
            dst[nj] = *(const short8*)&p[nj * 512];
    };

    LOADBF(bfA, 0);
    #pragma unroll                          // full unroll: bfA/bfB static
    for (int T = 0; T < 27; ++T) {
        short8* cur = (T & 1) ? bfB : bfA;
        short8* nxt = (T & 1) ? bfA : bfB;
        if (T + 1 < 27) LOADBF(nxt, T + 1); // issue-early (T14)
        __builtin_amdgcn_sched_barrier(0);  // pin loads above the MFMA burst

        int tap = T / 3, cs = T % 3;
        int ky = tap / 3, kx = tap % 3;
        #pragma unroll
        for (int mi = 0; mi < 4; ++mi) {
            short8 af = *(const short8*)&at[((cs * 4 + kgrp) * 180
                                            + (wm * 4 + mi + ky) * 18
                                            + kx + mrow) * 8];
            #pragma unroll
            for (int nj = 0; nj < 3; ++nj)
                acc[mi][nj] = __builtin_amdgcn_mfma_f32_16x16x32_bf16(
                    af, cur[nj], acc[mi][nj], 0, 0, 0);
        }
    }

    // ---- epilogue: exact GELU + f32x4 stores ----
    #pragma unroll
    for (int mi = 0; mi < 4; ++mi) {
        int gy = y0 + wm * 4 + mi;
        #pragma unroll
        for (int nj = 0; nj < 3; ++nj) {
            int cout = (wn * 3 + nj) * 16 + mrow;
            f32x4 gv;
            #pragma unroll
            for (int j = 0; j < 4; ++j) {
                float vv = acc[mi][nj][j];
                gv[j] = 0.5f * vv * (1.0f + erff(vv * 0.70710678118f));
            }
            *(f32x4*)&out[((size_t)b * COUT_ + cout) * HW_ + (size_t)gy * W_ +
                          x0 + kgrp * 4] = gv;
        }
    }
}

extern "C" void kernel_launch(void* const* d_in, const int* in_sizes, int n_in,
                              void* d_out, int out_size, void* d_ws, size_t ws_size,
                              hipStream_t stream) {
    const float* x  = (const float*)d_in[0];
    const float* pf = (const float*)d_in[1];
    const float* of = (const float*)d_in[2];
    float* out = (float*)d_out;

    unsigned short* sa   = (unsigned short*)d_ws;                       // 154,140,672 B
    unsigned short* ofb3 = (unsigned short*)((char*)d_ws + 154140672);  // + 165,888 B
    unsigned short* zp   = (unsigned short*)((char*)d_ws + 154306560);  // + 256 B zero-page

    prep_ofb<<<324, 256, 0, stream>>>(of, ofb3, zp);
    sa_kernel<<<B_ * P_, 256, 0, stream>>>(x, pf, sa);
    conv2_mfma<<<B_ * P_ * 2, 256, 0, stream>>>(sa, ofb3, zp, out);
}

// Round 20
// 362.991 us; speedup vs baseline: 1.0529x; 1.0529x over previous
//
#include <hip/hip_runtime.h>
#include <hip/hip_bf16.h>

#define B_    16
#define C_    96
#define H_    224
#define W_    224
#define COUT_ 96
#define GH_   14
#define GW_   14
#define P_    196          // GH_*GW_
#define HW_   (H_*W_)      // 50176
#define NCH_  12           // 8-channel chunks
#define APITCH 181         // A-tile plane pitch in px (2896 B mod 128 = 80 -> kgrp groups hit distinct bank rows)

#define AS1 __attribute__((address_space(1)))
#define AS3 __attribute__((address_space(3)))

typedef __attribute__((ext_vector_type(8))) unsigned short ushort8;
typedef __attribute__((ext_vector_type(8))) short        short8;   // MFMA bf16x8 operand
typedef __attribute__((ext_vector_type(4))) float        f32x4;

__device__ __forceinline__ unsigned short f2bf(float f) {
    union { __hip_bfloat16 h; unsigned short u; } cv;
    cv.h = __float2bfloat16(f);
    return cv.u;
}

// ---------------------------------------------------------------------------
// Kernel 1 (merged): blocks [0, 3136) = per-patch depthwise 3x3 -> sa;
// blocks [3136, 3460) = filter repack of -> ofb3 (fragment order) + zero-page.
// Merging removes one graph dispatch (~40 us of the R19 total was non-kernel).
// ---------------------------------------------------------------------------
__global__ __launch_bounds__(256) void sa_prep_kernel(const float* __restrict__ x,
                                                      const float* __restrict__ pf,
                                                      unsigned short* __restrict__ sa,
                                                      const float* __restrict__ of,
                                                      unsigned short* __restrict__ ofb3,
                                                      unsigned short* __restrict__ zp) {
    int bid = blockIdx.x;

    if (bid >= B_ * P_) {                  // ---- prep tail: ofb3 + zp ----
        int pb = bid - B_ * P_;
        if (pb == 0 && threadIdx.x < 128) zp[threadIdx.x] = 0;
        int e = pb * 256 + threadIdx.x;    // 9*3*6*64*8 = 82944
        if (e < 82944) {
            int j    = e & 7;
            int l    = (e >> 3) & 63;
            int ni   = (e >> 9) % 6;
            int cs   = (e / 3072) % 3;
            int tap  = e / 9216;
            int cout = ni * 16 + (l & 15);
            int c    = cs * 32 + (l >> 4) * 8 + j;
            ofb3[e] = f2bf(of[((size_t)cout * 96 + c) * 9 + tap]);
        }
        return;
    }

    // ---- sa part (R5-proven, ~107 us) ----
    int patch = bid % P_;
    int b     = bid / P_;
    int gh = patch / GW_, gw = patch % GW_;
    int t  = threadIdx.x;
    int py = t >> 4, px = t & 15;
    int y  = gh * 16 + py, xx = gw * 16 + px;

    __shared__ float xs[2][8][256];    // 16 KB double-buffered x slice

    const float* xp0 = x + (size_t)b * C_ * HW_ + (size_t)y * W_ + xx;

    float lf[8];
    #pragma unroll
    for (int ch = 0; ch < 8; ++ch) lf[ch] = xp0[(size_t)ch * HW_];

    for (int cc = 0; cc < NCH_; ++cc) {
        int buf = cc & 1;
        #pragma unroll
        for (int ch = 0; ch < 8; ++ch) xs[buf][ch][t] = lf[ch];
        __syncthreads();
        if (cc < NCH_ - 1) {
            #pragma unroll
            for (int ch = 0; ch < 8; ++ch)
                lf[ch] = xp0[(size_t)((cc + 1) * 8 + ch) * HW_];
        }

        ushort8 v;
        #pragma unroll
        for (int ch = 0; ch < 8; ++ch) {
            const float* wgt = pf + ((size_t)(cc * 8 + ch) * P_ + patch) * 9;  // uniform -> s_load
            float a = 0.f;
            #pragma unroll
            for (int dy = -1; dy <= 1; ++dy) {
                int yy = py + dy;
                if ((unsigned)yy < 16u) {
                    #pragma unroll
                    for (int dx = -1; dx <= 1; ++dx) {
                        int xq = px + dx;
                        if ((unsigned)xq < 16u)
                            a = fmaf(xs[buf][ch][yy * 16 + xq],
                                     wgt[(dy + 1) * 3 + (dx + 1)], a);
                    }
                }
            }
            v[ch] = f2bf(a);
        }
        *(ushort8*)&sa[(((size_t)(b * NCH_ + cc) * H_ + y) * W_ + xx) * 8] = v;
    }
}

// ---------------------------------------------------------------------------
// Kernel 2: implicit-GEMM MFMA conv + exact GELU, half-patch blocks.
// R20 = R19 (best: 232 us, 3 blocks/CU) + three fixes:
//   (a) af ds_reads join the issue-early pipeline (ring afA/afB, loaded for
//       T+1 BEFORE the fence): the ~150 cyc LDS latency per step now hides
//       under step T's 12 MFMAs instead of serializing in front of them;
//   (b) A-plane pitch 181 px: 2896 B stride => kgrp groups at distinct
//       mod-128 residues {0,80,32,112} (R19's 180-px stride aliased pairs
//       -> SQ_LDS_BANK_CONFLICT doubled to 10.8M);
//   (c) unchanged otherwise: fragment-order ofb3 bf loads (coalesced),
//       stage-once DMA, one barrier, acc[4][3], 2Mx2N waves, (256,3).
// ---------------------------------------------------------------------------
__global__ __launch_bounds__(256, 3) void conv2_mfma(const unsigned short* __restrict__ sa,
                                                     const unsigned short* __restrict__ ofb3,
                                                     const unsigned short* __restrict__ zp,
                                                     float* __restrict__ out) {
    // XCD-aware swizzle (6272 % 8 == 0 -> bijective); same-patch halves adjacent
    int bid0 = blockIdx.x;
    int bid  = (bid0 % 8) * (6272 / 8) + bid0 / 8;
    int half = bid & 1;
    int pid  = bid >> 1;
    int patch = pid % P_;
    int b     = pid / P_;
    int gh = patch / GW_, gw = patch % GW_;
    int y0 = gh * 16 + half * 8, x0 = gw * 16;   // 8x16 output region

    int t = threadIdx.x;
    int w = t >> 6, l = t & 63;
    int wm = w & 1, wn = w >> 1;            // 2 M-waves x 2 N-waves
    int mrow = l & 15, kgrp = l >> 4;

    __shared__ ushort8 at8[2304];           // 12 planes x 181 slots = 2172 (+132 trash) = 36,864 B

    // ---- single staging burst: 10x18 halo, plane-major, 181-slot pitch ----
    #pragma unroll
    for (int i = 0; i < 9; ++i) {
        int v = t + i * 256;                // 0..2303; real: v<2172 && slot<180
        const unsigned short* src = zp;
        if (v < 2172) {
            int ccl = v / APITCH, hpx = v - ccl * APITCH;
            if (hpx < 180) {
                int gy = y0 - 1 + hpx / 18, gx = x0 - 1 + hpx % 18;
                if ((unsigned)gy < (unsigned)H_ && (unsigned)gx < (unsigned)W_)
                    src = &sa[(((size_t)(b * NCH_ + ccl) * H_ + gy) * W_ + gx) * 8];
            }
        }
        __builtin_amdgcn_global_load_lds((const AS1 unsigned int*)src,
                                         (AS3 unsigned int*)&at8[v], 16, 0, 0);
    }

    f32x4 acc[4][3];
    #pragma unroll
    for (int mi = 0; mi < 4; ++mi)
        #pragma unroll
        for (int ni = 0; ni < 3; ++ni)
            acc[mi][ni] = (f32x4)0.f;

    __syncthreads();                        // drain DMA; tile visible; queue EMPTY

    const unsigned short* at = (const unsigned short*)at8;  // [plane][181 px][8ch]

    // Pipelines: bf (global, fragment-order) and af (LDS) both 1 step ahead.
    short8 bfA[3], bfB[3], afA[4], afB[4];
    auto LOADBF = [&](short8* dst, int T) {
        const unsigned short* p = ofb3 + (size_t)(T / 3) * 9216 + (T % 3) * 3072
                                  + (wn * 3) * 512 + l * 8;
        #pragma unroll
        for (int nj = 0; nj < 3; ++nj)
            dst[nj] = *(const short8*)&p[nj * 512];
    };
    auto LOADAF = [&](short8* dst, int T) {
        int tap = T / 3, cs = T % 3;
        int ky = tap / 3, kx = tap % 3;
        #pragma unroll
        for (int mi = 0; mi < 4; ++mi)
            dst[mi] = *(const short8*)&at[((cs * 4 + kgrp) * APITCH
                                          + (wm * 4 + mi + ky) * 18
                                          + kx + mrow) * 8];
    };

    LOADBF(bfA, 0);
    LOADAF(afA, 0);
    #pragma unroll                          // full unroll: ring naming static (rule #20)
    for (int T = 0; T < 27; ++T) {
        short8* bcur = (T & 1) ? bfB : bfA;
        short8* bnxt = (T & 1) ? bfA : bfB;
        short8* acur = (T & 1) ? afB : afA;
        short8* anxt = (T & 1) ? afA : afB;
        if (T + 1 < 27) {
            LOADBF(bnxt, T + 1);            // global loads in flight (T14)
            LOADAF(anxt, T + 1);            // ds_reads in flight
        }
        __builtin_amdgcn_sched_barrier(0);  // pin all T+1 issues above the burst

        #pragma unroll
        for (int mi = 0; mi < 4; ++mi)
            #pragma unroll
            for (int nj = 0; nj < 3; ++nj)
                acc[mi][nj] = __builtin_amdgcn_mfma_f32_16x16x32_bf16(
                    acur[mi], bcur[nj], acc[mi][nj], 0, 0, 0);
    }

    // ---- epilogue: exact GELU + f32x4 stores ----
    #pragma unroll
    for (int mi = 0; mi < 4; ++mi) {
        int gy = y0 + wm * 4 + mi;
        #pragma unroll
        for (int nj = 0; nj < 3; ++nj) {
            int cout = (wn * 3 + nj) * 16 + mrow;
            f32x4 gv;
            #pragma unroll
            for (int j = 0; j < 4; ++j) {
                float vv = acc[mi][nj][j];
                gv[j] = 0.5f * vv * (1.0f + erff(vv * 0.70710678118f));
            }
            *(f32x4*)&out[((size_t)b * COUT_ + cout) * HW_ + (size_t)gy * W_ +
                          x0 + kgrp * 4] = gv;
        }
    }
}

extern "C" void kernel_launch(void* const* d_in, const int* in_sizes, int n_in,
                              void* d_out, int out_size, void* d_ws, size_t ws_size,
                              hipStream_t stream) {
    const float* x  = (const float*)d_in[0];
    const float* pf = (const float*)d_in[1];
    const float* of = (const float*)d_in[2];
    float* out = (float*)d_out;

    unsigned short* sa   = (unsigned short*)d_ws;                       // 154,140,672 B
    unsigned short* ofb3 = (unsigned short*)((char*)d_ws + 154140672);  // + 165,888 B
    unsigned short* zp   = (unsigned short*)((char*)d_ws + 154306560);  // + 256 B zero-page

    sa_prep_kernel<<<B_ * P_ + 324, 256, 0, stream>>>(x, pf, sa, of, ofb3, zp);
    conv2_mfma<<<B_ * P_ * 2, 256, 0, stream>>>(sa, ofb3, zp, out);
}